// Round 17
// baseline (384.065 us; speedup 1.0000x reference)
//
#include <hip/hip_runtime.h>

typedef __attribute__((ext_vector_type(8))) __bf16 bf16x8;
typedef __attribute__((ext_vector_type(4))) float f32x4;
typedef __attribute__((ext_vector_type(8))) unsigned short u16x8;

#define B_ROWS 131072
#define EDIM   256
#define N_E    1024
#define BMR    64          // rows per scan block (16 per wave)
#define CHUNKS 32          // 32 chunks x 32 codes (2 halves of 16)
#define CAP    16
#define OROWS  32          // rows per output block

#define OUT1 ((size_t)B_ROWS * EDIM)       // loss scalar
#define OUT2 (OUT1 + 1)                    // indices [B]
#define OUT3 (OUT2 + B_ROWS)               // perplexity scalar

// ws layout
#define WS_EMBT  0          // emb16T: [32 granules][1024 codes][8 bf16] = 524288 B
#define WS_ESQ   524288     // 1024 float
#define WS_COUNT 528384     // 1024 uint
#define WS_LOSS  532480     // 1 double

__device__ __forceinline__ unsigned short f2bf(float f) {   // RN to bf16
    unsigned u = __float_as_uint(f);
    return (unsigned short)((u + 0x7FFFu + ((u >> 16) & 1u)) >> 16);
}
__device__ __forceinline__ unsigned encf(float f) {          // order-preserving
    unsigned u = __float_as_uint(f);
    return u ^ (unsigned)(((int)u >> 31) | 0x80000000);
}
__device__ __forceinline__ float decf(unsigned x) {
    return (x & 0x80000000u) ? __uint_as_float(x ^ 0x80000000u)
                             : __uint_as_float(~x);
}
__device__ __forceinline__ float med3f(float a, float b, float c) {
#if __has_builtin(__builtin_amdgcn_fmed3f)
    return __builtin_amdgcn_fmed3f(a, b, c);
#else
    return fmaxf(fminf(a, b), fminf(fmaxf(a, b), c));
#endif
}

// numpy pairwise sum-of-squares over 128 elems (exact tree, no contraction)
__device__ inline float pw128_sq(const float* p) {
    float4 v0 = *(const float4*)p, v1 = *(const float4*)(p + 4);
    float r[8];
    r[0] = __fmul_rn(v0.x, v0.x); r[1] = __fmul_rn(v0.y, v0.y);
    r[2] = __fmul_rn(v0.z, v0.z); r[3] = __fmul_rn(v0.w, v0.w);
    r[4] = __fmul_rn(v1.x, v1.x); r[5] = __fmul_rn(v1.y, v1.y);
    r[6] = __fmul_rn(v1.z, v1.z); r[7] = __fmul_rn(v1.w, v1.w);
    for (int i = 8; i < 128; i += 8) {
        v0 = *(const float4*)(p + i); v1 = *(const float4*)(p + i + 4);
        r[0] = __fadd_rn(r[0], __fmul_rn(v0.x, v0.x));
        r[1] = __fadd_rn(r[1], __fmul_rn(v0.y, v0.y));
        r[2] = __fadd_rn(r[2], __fmul_rn(v0.z, v0.z));
        r[3] = __fadd_rn(r[3], __fmul_rn(v0.w, v0.w));
        r[4] = __fadd_rn(r[4], __fmul_rn(v1.x, v1.x));
        r[5] = __fadd_rn(r[5], __fmul_rn(v1.y, v1.y));
        r[6] = __fadd_rn(r[6], __fmul_rn(v1.z, v1.z));
        r[7] = __fadd_rn(r[7], __fmul_rn(v1.w, v1.w));
    }
    float s01 = __fadd_rn(r[0], r[1]), s23 = __fadd_rn(r[2], r[3]);
    float s45 = __fadd_rn(r[4], r[5]), s67 = __fadd_rn(r[6], r[7]);
    return __fadd_rn(__fadd_rn(s01, s23), __fadd_rn(s45, s67));
}

// exact fp32 distance, bit-identical to the verified rounds-1..16 chain
__device__ inline float exact_d(const float* zp, const float* ep, float zsq, float eq) {
    const float4* z4 = (const float4*)zp;
    const float4* e4 = (const float4*)ep;
    float acc = 0.f;
#pragma unroll 8
    for (int k = 0; k < 64; ++k) {
        float4 a = z4[k], b = e4[k];
        acc = __fmaf_rn(a.x, b.x, acc);
        acc = __fmaf_rn(a.y, b.y, acc);
        acc = __fmaf_rn(a.z, b.z, acc);
        acc = __fmaf_rn(a.w, b.w, acc);
    }
    return __fsub_rn(__fadd_rn(zsq, eq), 2.0f * acc);
}

// emb fp32 -> bf16, TRANSPOSED layout: embT[g][n] = 16B granule g of code n
__global__ void prep_emb(const float* __restrict__ emb,
                         unsigned short* __restrict__ embT,
                         float* __restrict__ esqg)
{
    int n = blockIdx.x, t = threadIdx.x;          // 1024 blocks x 64 threads
    const float4 v = ((const float4*)(emb + (size_t)n * EDIM))[t];
    ushort4 o = { f2bf(v.x), f2bf(v.y), f2bf(v.z), f2bf(v.w) };
    int g = t >> 1, j0 = (t & 1) * 4;
    *(ushort4*)(embT + ((size_t)g * N_E + n) * 8 + j0) = o;
    if (t < 2) {
        float h = pw128_sq(emb + (size_t)n * EDIM + 128 * t);
        float ho = __shfl_xor(h, 1);
        if (t == 0) esqg[n] = __fadd_rn(h, ho);
    }
}

// top-3 sorted insert (codes ascend per lane; strict < = first-index ties)
#define INS(s_, code_, r_)                                                  \
    {                                                                       \
        bool lt1 = (s_) < bd1[r_];                                          \
        bool lt2 = (s_) < bd2[r_];                                          \
        bd3[r_] = med3f((s_), bd2[r_], bd3[r_]);                            \
        bd2[r_] = med3f((s_), bd1[r_], bd2[r_]);                            \
        bd1[r_] = fminf((s_), bd1[r_]);                                     \
        int low_ = cp_[r_] & 0xFFFF;                                        \
        cp_[r_] = lt1 ? ((code_) | (low_ << 16))                            \
                      : (lt2 ? (low_ | ((code_) << 16)) : cp_[r_]);         \
    }

// ===== scan + threshold + lean finalize (indices+histogram; NO gather) ======
__global__ __launch_bounds__(256, 4) void vq_scan(
    const float* __restrict__ z, const float* __restrict__ emb,
    const unsigned short* __restrict__ embT, const float* __restrict__ esqg,
    float* __restrict__ out, unsigned int* __restrict__ count)
{
    __shared__ float esq_s[N_E];                     // 4 KB
    __shared__ float S_s[BMR];
    __shared__ unsigned cnt[BMR];
    __shared__ unsigned short list[BMR][CAP];        // 2 KB
    __shared__ int rowbest[BMR];                     // -1 = overflow
    __shared__ float zq_fb;
    __shared__ unsigned long long fb4[4];

    const int tid  = threadIdx.x;
    const int blk  = blockIdx.x;
    const int lane = tid & 63;
    const int w    = tid >> 6;
    const int col  = lane & 15;
    const int quad = lane >> 4;
    const int row0 = w * 16;       // this wave owns rows row0..row0+15, ALL codes

    const float* zb = z + (size_t)blk * BMR * EDIM;

    for (int i = tid; i < N_E; i += 256) esq_s[i] = esqg[i];
    if (tid < BMR) cnt[tid] = 0u;

    // ---- A fragments from global z (one-time): 16 rows/wave = 32 VGPR ----
    bf16x8 afr[8];
    {
        int row = row0 + col;
#pragma unroll
        for (int ks = 0; ks < 8; ++ks) {
            const float* p = zb + row * EDIM + ((ks * 4 + quad) << 3);
            float4 a0 = *(const float4*)p;
            float4 a1 = *(const float4*)(p + 4);
            u16x8 t = { f2bf(a0.x), f2bf(a0.y), f2bf(a0.z), f2bf(a0.w),
                        f2bf(a1.x), f2bf(a1.y), f2bf(a1.z), f2bf(a1.w) };
            afr[ks] = *(bf16x8*)&t;
        }
    }

    // ---- S = sum|z| per row (margin bound only) ----
    if (tid < 128) {
        int row = tid >> 1, half = tid & 1;
        const float4* p4 = (const float4*)(zb + row * EDIM + half * 128);
        float4 sv = {0.f, 0.f, 0.f, 0.f};
#pragma unroll
        for (int jj = 0; jj < 32; ++jj) {
            float4 vv = p4[jj];
            sv.x += fabsf(vv.x); sv.y += fabsf(vv.y);
            sv.z += fabsf(vv.z); sv.w += fabsf(vv.w);
        }
        float sa = (sv.x + sv.y) + (sv.z + sv.w);
        float so = __shfl_xor(sa, 1);
        if (half == 0) S_s[row] = (sa + so) * 1.001f;
    }
    __syncthreads();

    // per-lane constant byte-offsets (in shorts) for B-granule loads, code half 0
    int koff[8];
#pragma unroll
    for (int ks = 0; ks < 8; ++ks)
        koff[ks] = ((((ks * 4 + quad) << 10) + col) << 3);

    // ================= barrier-free chunk loop (R15-proven, 216 us) ========
    float bd1[4], bd2[4], bd3[4];
    int   cp_[4];
#pragma unroll
    for (int r = 0; r < 4; ++r) {
        bd1[r] = INFINITY; bd2[r] = INFINITY; bd3[r] = INFINITY; cp_[r] = 0;
    }

    for (int c = 0; c < CHUNKS; ++c) {
        const unsigned short* cb = embT + (c << 8);      // + c*32 codes (uniform)
        {
            u16x8 bfr[8];
#pragma unroll
            for (int ks = 0; ks < 8; ++ks)
                bfr[ks] = *(const u16x8*)(cb + koff[ks]);
            f32x4 acc = {0.f, 0.f, 0.f, 0.f};
#pragma unroll
            for (int ks = 0; ks < 8; ++ks)
                acc = __builtin_amdgcn_mfma_f32_16x16x32_bf16(afr[ks], *(bf16x8*)&bfr[ks], acc, 0, 0, 0);
            const int codeN = (c << 5) + col;
            const float eqv = esq_s[codeN];
#pragma unroll
            for (int r = 0; r < 4; ++r) {
                float s = __fmaf_rn(-2.0f, acc[r], eqv);
                INS(s, codeN, r);
            }
        }
        {
            u16x8 bfr[8];
#pragma unroll
            for (int ks = 0; ks < 8; ++ks)
                bfr[ks] = *(const u16x8*)(cb + koff[ks] + 128);
            f32x4 acc = {0.f, 0.f, 0.f, 0.f};
#pragma unroll
            for (int ks = 0; ks < 8; ++ks)
                acc = __builtin_amdgcn_mfma_f32_16x16x32_bf16(afr[ks], *(bf16x8*)&bfr[ks], acc, 0, 0, 0);
            const int codeN = (c << 5) + 16 + col;
            const float eqv = esq_s[codeN];
#pragma unroll
            for (int r = 0; r < 4; ++r) {
                float s = __fmaf_rn(-2.0f, acc[r], eqv);
                INS(s, codeN, r);
            }
        }
    }

    // ---- butterfly allreduce of bd1 across 16 code-columns (lex min) ----
    float th[4];
#pragma unroll
    for (int r = 0; r < 4; ++r) {
        unsigned long long kk =
            ((unsigned long long)encf(bd1[r]) << 32) | (unsigned)(cp_[r] & 0xFFFF);
#pragma unroll
        for (int msk = 1; msk <= 8; msk <<= 1) {
            unsigned long long o = __shfl_xor(kk, msk);
            if (o < kk) kk = o;
        }
        int row = row0 + quad * 4 + r;
        th[r] = decf((unsigned)(kk >> 32)) + (S_s[row] * (1.0f / 131072.0f) + 1e-4f);
    }

    // ---- candidate push + overflow flag (top-3 soundness) ----
#pragma unroll
    for (int r = 0; r < 4; ++r) {
        int row = row0 + quad * 4 + r;
        if (__builtin_expect(bd1[r] <= th[r], 0)) {
            unsigned i = atomicAdd(&cnt[row], 1u);
            if (i < CAP) list[row][i] = (unsigned short)(cp_[r] & 0xFFFF);
        }
        if (__builtin_expect(bd2[r] <= th[r], 0)) {
            unsigned i = atomicAdd(&cnt[row], 1u);
            if (i < CAP) list[row][i] = (unsigned short)((unsigned)cp_[r] >> 16);
        }
        if (__builtin_expect(bd3[r] <= th[r], 0))
            atomicAdd(&cnt[row], 1000u);     // may have dropped a candidate
    }
    __syncthreads();

    // ---- lean finalize per row (4 lanes): cnt==1 fast path, else rescore ----
    {
        int row = tid >> 2, j = tid & 3;
        int cn = (int)cnt[row];
        if (cn > CAP) {
            if (j == 0) rowbest[row] = -1;        // block fallback
        } else if (cn == 1) {
            if (j == 0) {
                int bn = (int)list[row][0];       // sound: singleton candidate set
                out[OUT2 + (size_t)blk * BMR + row] = (float)bn;
                atomicAdd(&count[bn], 1u);
                rowbest[row] = -2;
            }
        } else {
            const float* zrow = zb + row * EDIM;
            float h = (j < 2) ? pw128_sq(zrow + 128 * j) : 0.f;
            int base = lane & ~3;
            float v0 = __shfl(h, base);
            float v1 = __shfl(h, base + 1);
            float zq = __fadd_rn(v0, v1);
            unsigned long long bkey = ~0ull;
            for (int i = j; i < cn; i += 4) {
                int n = (int)list[row][i];
                float d = exact_d(zrow, emb + (size_t)n * EDIM, zq, esq_s[n]);
                unsigned long long k2 = ((unsigned long long)encf(d) << 32) | (unsigned)n;
                if (k2 < bkey) bkey = k2;
            }
#pragma unroll
            for (int m = 1; m <= 2; m <<= 1) {
                unsigned long long o = __shfl_xor(bkey, m);
                if (o < bkey) bkey = o;
            }
            if (j == 0) {
                int bn = (int)(bkey & 0xFFFFFFFFu);
                out[OUT2 + (size_t)blk * BMR + row] = (float)bn;
                atomicAdd(&count[bn], 1u);
                rowbest[row] = -2;
            }
        }
    }
    __syncthreads();

    // ---- overflow rows: full exact scan, block-cooperative (rare) ----
    for (int r = 0; r < BMR; ++r) {
        if (rowbest[r] != -1) continue;       // uniform branch
        const float* zr = zb + r * EDIM;
        if (tid == 0)
            zq_fb = __fadd_rn(pw128_sq(zr), pw128_sq(zr + 128));
        __syncthreads();
        float zqr = zq_fb;
        unsigned long long k = ~0ull;
        for (int ci = 0; ci < 4; ++ci) {
            int n = tid + ci * 256;
            float d = exact_d(zr, emb + (size_t)n * EDIM, zqr, esq_s[n]);
            unsigned long long k2 = ((unsigned long long)encf(d) << 32) | (unsigned)n;
            if (k2 < k) k = k2;
        }
#pragma unroll
        for (int msk = 1; msk <= 32; msk <<= 1) {
            unsigned long long o = __shfl_xor(k, msk);
            if (o < k) k = o;
        }
        if (lane == 0) fb4[w] = k;
        __syncthreads();
        if (tid == 0) {
            unsigned long long m0 = fb4[0] < fb4[1] ? fb4[0] : fb4[1];
            unsigned long long m1 = fb4[2] < fb4[3] ? fb4[2] : fb4[3];
            int bn = (int)((m0 < m1 ? m0 : m1) & 0xFFFFFFFFu);
            out[OUT2 + (size_t)blk * BMR + r] = (float)bn;
            atomicAdd(&count[bn], 1u);
        }
        __syncthreads();
    }
}

// pure streaming: gather z_q = emb[idx], STE output, loss partial (at roofline)
__global__ void vq_output(const float* __restrict__ z, const float* __restrict__ emb,
                          float* __restrict__ out, double* __restrict__ lossSum)
{
    __shared__ double red4s[4];
    const int tid = threadIdx.x;
    const int blk = blockIdx.x;
    const int lane = tid & 63;
    const int w   = tid >> 6;
    const int row = tid >> 3;      // 0..31
    const int q   = tid & 7;       // 8 threads per row
    const size_t grow = (size_t)blk * OROWS + row;
    const int bn = (int)out[OUT2 + grow];
    const float4* zp4 = (const float4*)(z + grow * EDIM);
    const float4* ebr = (const float4*)(emb + (size_t)bn * EDIM);
    float4* outr = (float4*)(out + grow * EDIM);
    double lacc = 0.0;
#pragma unroll
    for (int i = 0; i < 8; ++i) {
        int k4 = q + i * 8;
        float4 zv = zp4[k4];
        float4 ev = ebr[k4];
        float4 o; float sd;
        sd = __fsub_rn(ev.x, zv.x); o.x = __fadd_rn(zv.x, sd); lacc += (double)__fmul_rn(sd, sd);
        sd = __fsub_rn(ev.y, zv.y); o.y = __fadd_rn(zv.y, sd); lacc += (double)__fmul_rn(sd, sd);
        sd = __fsub_rn(ev.z, zv.z); o.z = __fadd_rn(zv.z, sd); lacc += (double)__fmul_rn(sd, sd);
        sd = __fsub_rn(ev.w, zv.w); o.w = __fadd_rn(zv.w, sd); lacc += (double)__fmul_rn(sd, sd);
        outr[k4] = o;
    }
#pragma unroll
    for (int msk = 1; msk <= 32; msk <<= 1) lacc += __shfl_xor(lacc, msk);
    if (lane == 0) red4s[w] = lacc;
    __syncthreads();
    if (tid == 0) atomicAdd(lossSum, red4s[0] + red4s[1] + red4s[2] + red4s[3]);
}

__global__ void vq_finalize(const unsigned int* __restrict__ count,
                            const double* __restrict__ lossSum,
                            float* __restrict__ out)
{
    __shared__ double red[1024];
    int t = threadIdx.x;
    double em = (double)count[t] * (1.0 / 131072.0);
    red[t] = em * log(em + 1e-10);
    __syncthreads();
    for (int s = 512; s > 0; s >>= 1) {
        if (t < s) red[t] += red[t + s];
        __syncthreads();
    }
    if (t == 0) {
        out[OUT3] = (float)exp(-red[0]);
        double m = lossSum[0] * (1.0 / 33554432.0);
        out[OUT1] = (float)(1.25 * m);
    }
}

extern "C" void kernel_launch(void* const* d_in, const int* in_sizes, int n_in,
                              void* d_out, int out_size, void* d_ws, size_t ws_size,
                              hipStream_t stream) {
    const float* z   = (const float*)d_in[0];
    const float* emb = (const float*)d_in[1];
    float* out = (float*)d_out;

    unsigned short* embT = (unsigned short*)((char*)d_ws + WS_EMBT);
    float* esqg          = (float*)((char*)d_ws + WS_ESQ);
    unsigned int* count  = (unsigned int*)((char*)d_ws + WS_COUNT);
    double* lossSum      = (double*)((char*)d_ws + WS_LOSS);

    hipMemsetAsync((char*)d_ws + WS_COUNT, 0, 4104, stream);
    prep_emb<<<N_E, 64, 0, stream>>>(emb, embT, esqg);
    vq_scan<<<B_ROWS / BMR, 256, 0, stream>>>(z, emb, embT, esqg, out, count);
    vq_output<<<B_ROWS / OROWS, 256, 0, stream>>>(z, emb, out, lossSum);
    vq_finalize<<<1, 1024, 0, stream>>>(count, lossSum, out);
}

// Round 18
// 341.276 us; speedup vs baseline: 1.1254x; 1.1254x over previous
//
#include <hip/hip_runtime.h>

typedef __attribute__((ext_vector_type(8))) __bf16 bf16x8;
typedef __attribute__((ext_vector_type(4))) float f32x4;
typedef __attribute__((ext_vector_type(8))) unsigned short u16x8;

#define B_ROWS 131072
#define EDIM   256
#define N_E    1024
#define BMR    64          // rows per scan block (16 per wave)
#define CAP    16
#define OROWS  32          // rows per output block

#define OUT1 ((size_t)B_ROWS * EDIM)       // loss scalar
#define OUT2 (OUT1 + 1)                    // indices [B]
#define OUT3 (OUT2 + B_ROWS)               // perplexity scalar

// ws layout
#define WS_EMBT  0          // emb16T: [32 granules][1024 codes][8 bf16] = 524288 B
#define WS_ESQ   524288     // 1024 float
#define WS_COUNT 528384     // 1024 uint
#define WS_LOSS  532480     // 1 double

__device__ __forceinline__ unsigned short f2bf(float f) {   // RN to bf16
    unsigned u = __float_as_uint(f);
    return (unsigned short)((u + 0x7FFFu + ((u >> 16) & 1u)) >> 16);
}
__device__ __forceinline__ unsigned encf(float f) {          // order-preserving
    unsigned u = __float_as_uint(f);
    return u ^ (unsigned)(((int)u >> 31) | 0x80000000);
}
__device__ __forceinline__ float decf(unsigned x) {
    return (x & 0x80000000u) ? __uint_as_float(x ^ 0x80000000u)
                             : __uint_as_float(~x);
}
__device__ __forceinline__ float med3f(float a, float b, float c) {
#if __has_builtin(__builtin_amdgcn_fmed3f)
    return __builtin_amdgcn_fmed3f(a, b, c);
#else
    return fmaxf(fminf(a, b), fminf(fmaxf(a, b), c));
#endif
}

// numpy pairwise sum-of-squares over 128 elems (exact tree, no contraction)
__device__ inline float pw128_sq(const float* p) {
    float4 v0 = *(const float4*)p, v1 = *(const float4*)(p + 4);
    float r[8];
    r[0] = __fmul_rn(v0.x, v0.x); r[1] = __fmul_rn(v0.y, v0.y);
    r[2] = __fmul_rn(v0.z, v0.z); r[3] = __fmul_rn(v0.w, v0.w);
    r[4] = __fmul_rn(v1.x, v1.x); r[5] = __fmul_rn(v1.y, v1.y);
    r[6] = __fmul_rn(v1.z, v1.z); r[7] = __fmul_rn(v1.w, v1.w);
    for (int i = 8; i < 128; i += 8) {
        v0 = *(const float4*)(p + i); v1 = *(const float4*)(p + i + 4);
        r[0] = __fadd_rn(r[0], __fmul_rn(v0.x, v0.x));
        r[1] = __fadd_rn(r[1], __fmul_rn(v0.y, v0.y));
        r[2] = __fadd_rn(r[2], __fmul_rn(v0.z, v0.z));
        r[3] = __fadd_rn(r[3], __fmul_rn(v0.w, v0.w));
        r[4] = __fadd_rn(r[4], __fmul_rn(v1.x, v1.x));
        r[5] = __fadd_rn(r[5], __fmul_rn(v1.y, v1.y));
        r[6] = __fadd_rn(r[6], __fmul_rn(v1.z, v1.z));
        r[7] = __fadd_rn(r[7], __fmul_rn(v1.w, v1.w));
    }
    float s01 = __fadd_rn(r[0], r[1]), s23 = __fadd_rn(r[2], r[3]);
    float s45 = __fadd_rn(r[4], r[5]), s67 = __fadd_rn(r[6], r[7]);
    return __fadd_rn(__fadd_rn(s01, s23), __fadd_rn(s45, s67));
}

// exact fp32 distance, bit-identical to the verified rounds-1..17 chain
__device__ inline float exact_d(const float* zp, const float* ep, float zsq, float eq) {
    const float4* z4 = (const float4*)zp;
    const float4* e4 = (const float4*)ep;
    float acc = 0.f;
#pragma unroll 8
    for (int k = 0; k < 64; ++k) {
        float4 a = z4[k], b = e4[k];
        acc = __fmaf_rn(a.x, b.x, acc);
        acc = __fmaf_rn(a.y, b.y, acc);
        acc = __fmaf_rn(a.z, b.z, acc);
        acc = __fmaf_rn(a.w, b.w, acc);
    }
    return __fsub_rn(__fadd_rn(zsq, eq), 2.0f * acc);
}

// emb fp32 -> bf16, TRANSPOSED layout: embT[g][n] = 16B granule g of code n
__global__ void prep_emb(const float* __restrict__ emb,
                         unsigned short* __restrict__ embT,
                         float* __restrict__ esqg)
{
    int n = blockIdx.x, t = threadIdx.x;          // 1024 blocks x 64 threads
    const float4 v = ((const float4*)(emb + (size_t)n * EDIM))[t];
    ushort4 o = { f2bf(v.x), f2bf(v.y), f2bf(v.z), f2bf(v.w) };
    int g = t >> 1, j0 = (t & 1) * 4;
    *(ushort4*)(embT + ((size_t)g * N_E + n) * 8 + j0) = o;
    if (t < 2) {
        float h = pw128_sq(emb + (size_t)n * EDIM + 128 * t);
        float ho = __shfl_xor(h, 1);
        if (t == 0) esqg[n] = __fadd_rn(h, ho);
    }
}

// top-3 sorted insert (codes ascend per lane; strict < = first-index ties)
#define INS(s_, code_, r_)                                                  \
    {                                                                       \
        bool lt1 = (s_) < bd1[r_];                                          \
        bool lt2 = (s_) < bd2[r_];                                          \
        bd3[r_] = med3f((s_), bd2[r_], bd3[r_]);                            \
        bd2[r_] = med3f((s_), bd1[r_], bd2[r_]);                            \
        bd1[r_] = fminf((s_), bd1[r_]);                                     \
        int low_ = cp_[r_] & 0xFFFF;                                        \
        cp_[r_] = lt1 ? ((code_) | (low_ << 16))                            \
                      : (lt2 ? (low_ | ((code_) << 16)) : cp_[r_]);         \
    }

// compute one 16-code unit from buffer B_: 8 MFMA + 4 score inserts
#define UNIT(B_, u_)                                                        \
    {                                                                       \
        f32x4 acc = {0.f, 0.f, 0.f, 0.f};                                   \
        _Pragma("unroll")                                                   \
        for (int ks = 0; ks < 8; ++ks)                                      \
            acc = __builtin_amdgcn_mfma_f32_16x16x32_bf16(afr[ks],          \
                      *(bf16x8*)&B_[ks], acc, 0, 0, 0);                     \
        const int codeN = ((u_) << 4) + col;                                \
        const float eqv = esq_s[codeN];                                     \
        _Pragma("unroll")                                                   \
        for (int r = 0; r < 4; ++r) {                                       \
            float s = __fmaf_rn(-2.0f, acc[r], eqv);                        \
            INS(s, codeN, r);                                               \
        }                                                                   \
    }

// ============ S1: pure MFMA scan + threshold + candidate rec ================
__global__ __launch_bounds__(256, 4) void vq_scan(
    const float* __restrict__ z, const unsigned short* __restrict__ embT,
    const float* __restrict__ esqg, float* __restrict__ out)
{
    __shared__ float esq_s[N_E];                     // 4 KB
    __shared__ float S_s[BMR];
    __shared__ unsigned cnt[BMR];
    __shared__ unsigned short list[BMR][CAP];        // 2 KB

    const int tid  = threadIdx.x;
    const int blk  = blockIdx.x;
    const int lane = tid & 63;
    const int w    = tid >> 6;
    const int col  = lane & 15;
    const int quad = lane >> 4;
    const int row0 = w * 16;       // this wave owns rows row0..row0+15, ALL codes

    const float* zb = z + (size_t)blk * BMR * EDIM;

    for (int i = tid; i < N_E; i += 256) esq_s[i] = esqg[i];
    if (tid < BMR) cnt[tid] = 0u;

    // ---- A fragments from global z (one-time): 16 rows/wave = 32 VGPR ----
    bf16x8 afr[8];
    {
        int row = row0 + col;
#pragma unroll
        for (int ks = 0; ks < 8; ++ks) {
            const float* p = zb + row * EDIM + ((ks * 4 + quad) << 3);
            float4 a0 = *(const float4*)p;
            float4 a1 = *(const float4*)(p + 4);
            u16x8 t = { f2bf(a0.x), f2bf(a0.y), f2bf(a0.z), f2bf(a0.w),
                        f2bf(a1.x), f2bf(a1.y), f2bf(a1.z), f2bf(a1.w) };
            afr[ks] = *(bf16x8*)&t;
        }
    }

    // ---- S = sum|z| per row (margin bound only) ----
    if (tid < 128) {
        int row = tid >> 1, half = tid & 1;
        const float4* p4 = (const float4*)(zb + row * EDIM + half * 128);
        float4 sv = {0.f, 0.f, 0.f, 0.f};
#pragma unroll
        for (int jj = 0; jj < 32; ++jj) {
            float4 vv = p4[jj];
            sv.x += fabsf(vv.x); sv.y += fabsf(vv.y);
            sv.z += fabsf(vv.z); sv.w += fabsf(vv.w);
        }
        float sa = (sv.x + sv.y) + (sv.z + sv.w);
        float so = __shfl_xor(sa, 1);
        if (half == 0) S_s[row] = (sa + so) * 1.001f;
    }
    __syncthreads();

    // unit u (16 codes): address (shorts) = base + ks*32768 + u*128
    const unsigned short* base = embT + ((quad << 13) + (col << 3));

    float bd1[4], bd2[4], bd3[4];
    int   cp_[4];
#pragma unroll
    for (int r = 0; r < 4; ++r) {
        bd1[r] = INFINITY; bd2[r] = INFINITY; bd3[r] = INFINITY; cp_[r] = 0;
    }

    // ======= 2-deep software-pipelined unit loop (64 units, ascending) =====
    u16x8 A[8], Bf[8];
#pragma unroll
    for (int ks = 0; ks < 8; ++ks) A[ks] = *(const u16x8*)(base + ks * 32768);

    for (int u = 0; u < 64; u += 2) {
        const unsigned short* pb = base + (u + 1) * 128;
#pragma unroll
        for (int ks = 0; ks < 8; ++ks) Bf[ks] = *(const u16x8*)(pb + ks * 32768);
        UNIT(A, u);
        if (u + 2 < 64) {
            const unsigned short* pa = base + (u + 2) * 128;
#pragma unroll
            for (int ks = 0; ks < 8; ++ks) A[ks] = *(const u16x8*)(pa + ks * 32768);
        }
        UNIT(Bf, u + 1);
    }

    // ---- butterfly allreduce of bd1 across 16 code-columns (lex min) ----
    float th[4];
#pragma unroll
    for (int r = 0; r < 4; ++r) {
        unsigned long long kk =
            ((unsigned long long)encf(bd1[r]) << 32) | (unsigned)(cp_[r] & 0xFFFF);
#pragma unroll
        for (int msk = 1; msk <= 8; msk <<= 1) {
            unsigned long long o = __shfl_xor(kk, msk);
            if (o < kk) kk = o;
        }
        int row = row0 + quad * 4 + r;
        th[r] = decf((unsigned)(kk >> 32)) + (S_s[row] * (1.0f / 131072.0f) + 1e-4f);
    }

    // ---- candidate push + overflow flag (top-3 soundness) ----
#pragma unroll
    for (int r = 0; r < 4; ++r) {
        int row = row0 + quad * 4 + r;
        if (__builtin_expect(bd1[r] <= th[r], 0)) {
            unsigned i = atomicAdd(&cnt[row], 1u);
            if (i < CAP) list[row][i] = (unsigned short)(cp_[r] & 0xFFFF);
        }
        if (__builtin_expect(bd2[r] <= th[r], 0)) {
            unsigned i = atomicAdd(&cnt[row], 1u);
            if (i < CAP) list[row][i] = (unsigned short)((unsigned)cp_[r] >> 16);
        }
        if (__builtin_expect(bd3[r] <= th[r], 0))
            atomicAdd(&cnt[row], 1000u);     // may have dropped a candidate
    }
    __syncthreads();

    // ---- write rec into the row's OWN z_q slot (output reads then overwrites)
    if (tid < BMR) {
        int row = tid;
        size_t grow = (size_t)blk * BMR + row;
        unsigned* rec = (unsigned*)(out + grow * EDIM);
        rec[0] = cnt[row];
#pragma unroll
        for (int k = 0; k < 8; ++k)
            rec[1 + k] = (unsigned)list[row][2 * k]
                       | ((unsigned)list[row][2 * k + 1] << 16);
    }
}

// ===== S2: resolve bn (fast path / rescore / overflow) + gather/STE/loss ====
__global__ void vq_output(const float* __restrict__ z, const float* __restrict__ emb,
                          const float* __restrict__ esqg, float* __restrict__ out,
                          unsigned int* __restrict__ count,
                          double* __restrict__ lossSum)
{
    __shared__ double red4s[4];
    const int tid  = threadIdx.x;
    const int blk  = blockIdx.x;
    const int lane = tid & 63;
    const int w    = tid >> 6;
    const int row  = tid >> 3;     // 0..31
    const int q    = tid & 7;      // 8 threads per row
    const size_t grow = (size_t)blk * OROWS + row;
    const float* zrow = z + grow * EDIM;
    const unsigned* rec = (const unsigned*)(out + grow * EDIM);

    unsigned cn = rec[0];
    int bn = 0;
    if (cn == 1u) {
        bn = (int)(rec[1] & 0xFFFFu);                 // sound singleton
    } else if (cn <= CAP) {
        // 8-lane exact rescore (bit-identical chain, lex tie-break)
        float h = (q < 2) ? pw128_sq(zrow + 128 * q) : 0.f;
        int b8 = lane & ~7;
        float zq = __fadd_rn(__shfl(h, b8), __shfl(h, b8 + 1));
        unsigned long long bkey = ~0ull;
        for (int i = q; i < (int)cn; i += 8) {
            unsigned pr = rec[1 + (i >> 1)];
            int n = (int)((i & 1) ? (pr >> 16) : (pr & 0xFFFFu));
            float d = exact_d(zrow, emb + (size_t)n * EDIM, zq, esqg[n]);
            unsigned long long k2 = ((unsigned long long)encf(d) << 32) | (unsigned)n;
            if (k2 < bkey) bkey = k2;
        }
#pragma unroll
        for (int m = 1; m <= 4; m <<= 1) {
            unsigned long long o = __shfl_xor(bkey, m);
            if (o < bkey) bkey = o;
        }
        bn = (int)(bkey & 0xFFFFFFFFu);
    }
    // ---- overflow rows: 64-lane exact scan, one row at a time (rare) ----
    unsigned long long ball = __ballot(cn > CAP);
    while (ball) {
        int lb = (int)(__ffsll((long long)ball) - 1);
        int rsel = lb >> 3;                            // row index within wave
        size_t growo = (size_t)blk * OROWS + (w << 3) + rsel;
        const float* zr = z + growo * EDIM;
        float h2 = (lane < 2) ? pw128_sq(zr + 128 * lane) : 0.f;
        float zq2 = __fadd_rn(__shfl(h2, 0), __shfl(h2, 1));
        unsigned long long k = ~0ull;
        for (int n0 = 0; n0 < 16; ++n0) {
            int n = lane * 16 + n0;
            float d = exact_d(zr, emb + (size_t)n * EDIM, zq2, esqg[n]);
            unsigned long long k2 = ((unsigned long long)encf(d) << 32) | (unsigned)n;
            if (k2 < k) k = k2;
        }
#pragma unroll
        for (int msk = 1; msk <= 32; msk <<= 1) {
            unsigned long long o = __shfl_xor(k, msk);
            if (o < k) k = o;
        }
        if ((lane >> 3) == rsel) bn = (int)(k & 0xFFFFFFFFu);
        ball &= ~(0xFFull << (lb & ~7));
    }

    // ---- gather z_q, STE, loss partial, index, histogram ----
    const float4* zp4 = (const float4*)zrow;
    const float4* ebr = (const float4*)(emb + (size_t)bn * EDIM);
    float4* outr = (float4*)(out + grow * EDIM);
    double lacc = 0.0;
#pragma unroll
    for (int i = 0; i < 8; ++i) {
        int k4 = q + i * 8;
        float4 zv = zp4[k4];
        float4 ev = ebr[k4];
        float4 o; float sd;
        sd = __fsub_rn(ev.x, zv.x); o.x = __fadd_rn(zv.x, sd); lacc += (double)__fmul_rn(sd, sd);
        sd = __fsub_rn(ev.y, zv.y); o.y = __fadd_rn(zv.y, sd); lacc += (double)__fmul_rn(sd, sd);
        sd = __fsub_rn(ev.z, zv.z); o.z = __fadd_rn(zv.z, sd); lacc += (double)__fmul_rn(sd, sd);
        sd = __fsub_rn(ev.w, zv.w); o.w = __fadd_rn(zv.w, sd); lacc += (double)__fmul_rn(sd, sd);
        outr[k4] = o;
    }
    if (q == 0) {
        out[OUT2 + grow] = (float)bn;
        atomicAdd(&count[bn], 1u);
    }
#pragma unroll
    for (int msk = 1; msk <= 32; msk <<= 1) lacc += __shfl_xor(lacc, msk);
    if (lane == 0) red4s[w] = lacc;
    __syncthreads();
    if (tid == 0) atomicAdd(lossSum, red4s[0] + red4s[1] + red4s[2] + red4s[3]);
}

__global__ void vq_finalize(const unsigned int* __restrict__ count,
                            const double* __restrict__ lossSum,
                            float* __restrict__ out)
{
    __shared__ double red[1024];
    int t = threadIdx.x;
    double em = (double)count[t] * (1.0 / 131072.0);
    red[t] = em * log(em + 1e-10);
    __syncthreads();
    for (int s = 512; s > 0; s >>= 1) {
        if (t < s) red[t] += red[t + s];
        __syncthreads();
    }
    if (t == 0) {
        out[OUT3] = (float)exp(-red[0]);
        double m = lossSum[0] * (1.0 / 33554432.0);
        out[OUT1] = (float)(1.25 * m);
    }
}

extern "C" void kernel_launch(void* const* d_in, const int* in_sizes, int n_in,
                              void* d_out, int out_size, void* d_ws, size_t ws_size,
                              hipStream_t stream) {
    const float* z   = (const float*)d_in[0];
    const float* emb = (const float*)d_in[1];
    float* out = (float*)d_out;

    unsigned short* embT = (unsigned short*)((char*)d_ws + WS_EMBT);
    float* esqg          = (float*)((char*)d_ws + WS_ESQ);
    unsigned int* count  = (unsigned int*)((char*)d_ws + WS_COUNT);
    double* lossSum      = (double*)((char*)d_ws + WS_LOSS);

    hipMemsetAsync((char*)d_ws + WS_COUNT, 0, 4104, stream);
    prep_emb<<<N_E, 64, 0, stream>>>(emb, embT, esqg);
    vq_scan<<<B_ROWS / BMR, 256, 0, stream>>>(z, embT, esqg, out);
    vq_output<<<B_ROWS / OROWS, 256, 0, stream>>>(z, emb, esqg, out, count, lossSum);
    vq_finalize<<<1, 1024, 0, stream>>>(count, lossSum, out);
}